// Round 5
// baseline (296.069 us; speedup 1.0000x reference)
//
#include <hip/hip_runtime.h>

// Problem: B=64, C=16, H=32, W=512, SHIFT=4 (9 offsets), MARGIN=0.15
#define NB 64
#define NC 16
#define NH 32
#define NW 512
#define HW (NH * NW)      // 16384
#define CHW (NC * HW)     // 262144
#define NOFF 9

// ws layout (floats): num_ap[64*9] | num_an[64*9] | cnt_ap[64*9] | cnt_an[64*9]
#define WS_NUM_AP 0
#define WS_NUM_AN 576
#define WS_CNT_AP 1152
#define WS_CNT_AN 1728
#define WS_FLOATS 2304

__device__ __forceinline__ float wave_sum_f(float v) {
#pragma unroll
    for (int o = 32; o > 0; o >>= 1) v += __shfl_down(v, o, 64);
    return v;
}

__device__ __forceinline__ int wave_sum_i(int v) {
#pragma unroll
    for (int o = 32; o > 0; o >>= 1) v += __shfl_down(v, o, 64);
    return v;
}

// grid: (16, 64). blockIdx.y = batch. Each thread owns 4 consecutive float4-aligned
// positions; all 9 shifts per channel come from 3 float4 loads (w0-4, w0, w0+4).
// R4 lesson: grid size was NOT the occupancy limiter; the channel loop was
// latency-serialized (no cross-iteration overlap with unroll-2). This version
// ping-pongs two register buffer sets, issuing channel c+1's loads before
// computing channel c, fully unrolled. Counts are recomputed from mask words
// at the epilogue (frees 18 VGPRs of accumulators).
// NOTE: no min-waves launch bound — R3's (256,8) forced VGPR 60->32 and
// spilled ~640 MB to scratch. Let the allocator float.
__global__ __launch_bounds__(256) void num_kernel(
    const float* __restrict__ a, const float* __restrict__ p,
    const float* __restrict__ n, const int* __restrict__ ma,
    const int* __restrict__ mp, const int* __restrict__ mn,
    float* __restrict__ ws)
{
    const int b = blockIdx.y;
    const int tid = blockIdx.x * 256 + threadIdx.x;  // 0..4095
    const int pos0 = tid * 4;                        // multiple of 4, in [0, HW)
    const int w0 = pos0 & (NW - 1);
    const int row = pos0 - w0;
    const int idxm = row + ((w0 - 4) & (NW - 1));    // aligned float4, row-circular
    const int idxp = row + ((w0 + 4) & (NW - 1));

    const int* MA = ma + b * HW;
    const int* MP = mp + b * HW;
    const int* MN = mn + b * HW;

    // ---- masks: computed once, reused for all 16 channels ----
    int4 mav = *(const int4*)(MA + pos0);
    int4 mq0 = *(const int4*)(MP + idxm);
    int4 mq1 = *(const int4*)(MP + pos0);
    int4 mq2 = *(const int4*)(MP + idxp);
    int4 mr0 = *(const int4*)(MN + idxm);
    int4 mr1 = *(const int4*)(MN + pos0);
    int4 mr2 = *(const int4*)(MN + idxp);

    int mpb[12] = {mq0.x, mq0.y, mq0.z, mq0.w, mq1.x, mq1.y, mq1.z, mq1.w,
                   mq2.x, mq2.y, mq2.z, mq2.w};
    int mnb[12] = {mr0.x, mr0.y, mr0.z, mr0.w, mr1.x, mr1.y, mr1.z, mr1.w,
                   mr2.x, mr2.y, mr2.z, mr2.w};
    int mab[4] = {mav.x, mav.y, mav.z, mav.w};

    unsigned mAp[4], mAn[4];
#pragma unroll
    for (int j = 0; j < 4; ++j) {
        unsigned wp = 0, wn = 0;
#pragma unroll
        for (int s = 0; s < NOFF; ++s) {
            // f2 index for (pos0+j, shift s) is buf[j + 8 - s]
            const int k = j + 8 - s;
            if (mab[j] && mpb[k]) wp |= (1u << s);
            if (mab[j] && mnb[k]) wn |= (1u << s);
        }
        mAp[j] = wp; mAn[j] = wn;
    }

    // ---- channel loop: ping-pong register double-buffer ----
    const float* A = a + (size_t)b * CHW;
    const float* P = p + (size_t)b * CHW;
    const float* N = n + (size_t)b * CHW;

    float s_ap[NOFF], s_an[NOFF];
#pragma unroll
    for (int s = 0; s < NOFF; ++s) { s_ap[s] = 0.f; s_an[s] = 0.f; }

    float4 Xa, Xp0, Xp1, Xp2, Xn0, Xn1, Xn2;   // buffer X
    float4 Ya, Yp0, Yp1, Yp2, Yn0, Yn1, Yn2;   // buffer Y

#define LOAD_BUF(Ba, Bp0, Bp1, Bp2, Bn0, Bn1, Bn2, c) do {        \
        const float* Ac_ = A + (c) * HW;                          \
        const float* Pc_ = P + (c) * HW;                          \
        const float* Nc_ = N + (c) * HW;                          \
        Ba  = *(const float4*)(Ac_ + pos0);                       \
        Bp0 = *(const float4*)(Pc_ + idxm);                       \
        Bp1 = *(const float4*)(Pc_ + pos0);                       \
        Bp2 = *(const float4*)(Pc_ + idxp);                       \
        Bn0 = *(const float4*)(Nc_ + idxm);                       \
        Bn1 = *(const float4*)(Nc_ + pos0);                       \
        Bn2 = *(const float4*)(Nc_ + idxp);                       \
    } while (0)

#define COMPUTE_BUF(Ba, Bp0, Bp1, Bp2, Bn0, Bn1, Bn2) do {        \
        float av_[4] = {Ba.x, Ba.y, Ba.z, Ba.w};                  \
        float pb_[12] = {Bp0.x, Bp0.y, Bp0.z, Bp0.w,              \
                         Bp1.x, Bp1.y, Bp1.z, Bp1.w,              \
                         Bp2.x, Bp2.y, Bp2.z, Bp2.w};             \
        float nb_[12] = {Bn0.x, Bn0.y, Bn0.z, Bn0.w,              \
                         Bn1.x, Bn1.y, Bn1.z, Bn1.w,              \
                         Bn2.x, Bn2.y, Bn2.z, Bn2.w};             \
        _Pragma("unroll")                                         \
        for (int s = 0; s < NOFF; ++s) {                          \
            _Pragma("unroll")                                     \
            for (int j = 0; j < 4; ++j) {                         \
                const int k = j + 8 - s;                          \
                const float d = av_[j] - pb_[k];                  \
                const float dm = ((mAp[j] >> s) & 1u) ? d : 0.f;  \
                s_ap[s] = fmaf(d, dm, s_ap[s]);                   \
                const float e = av_[j] - nb_[k];                  \
                const float em = ((mAn[j] >> s) & 1u) ? e : 0.f;  \
                s_an[s] = fmaf(e, em, s_an[s]);                   \
            }                                                     \
        }                                                         \
    } while (0)

    LOAD_BUF(Xa, Xp0, Xp1, Xp2, Xn0, Xn1, Xn2, 0);
#pragma unroll
    for (int c = 0; c < NC; c += 2) {
        LOAD_BUF(Ya, Yp0, Yp1, Yp2, Yn0, Yn1, Yn2, c + 1);
        COMPUTE_BUF(Xa, Xp0, Xp1, Xp2, Xn0, Xn1, Xn2);
        if (c + 2 < NC) LOAD_BUF(Xa, Xp0, Xp1, Xp2, Xn0, Xn1, Xn2, c + 2);
        COMPUTE_BUF(Ya, Yp0, Yp1, Yp2, Yn0, Yn1, Yn2);
    }

    // ---- reduce across the wave; one atomicAdd per wave per counter ----
    const int lane = threadIdx.x & 63;
#pragma unroll
    for (int s = 0; s < NOFF; ++s) {
        float v = wave_sum_f(s_ap[s]);
        if (lane == 0) atomicAdd(&ws[WS_NUM_AP + b * NOFF + s], v);
        float u = wave_sum_f(s_an[s]);
        if (lane == 0) atomicAdd(&ws[WS_NUM_AN + b * NOFF + s], u);
        // counts recomputed from mask words (channel-independent)
        int ci = wave_sum_i((int)((mAp[0] >> s) & 1u) + (int)((mAp[1] >> s) & 1u) +
                            (int)((mAp[2] >> s) & 1u) + (int)((mAp[3] >> s) & 1u));
        if (lane == 0) atomicAdd(&ws[WS_CNT_AP + b * NOFF + s], (float)ci);
        int cj = wave_sum_i((int)((mAn[0] >> s) & 1u) + (int)((mAn[1] >> s) & 1u) +
                            (int)((mAn[2] >> s) & 1u) + (int)((mAn[3] >> s) & 1u));
        if (lane == 0) atomicAdd(&ws[WS_CNT_AN + b * NOFF + s], (float)cj);
    }
}

// 1 block, 64 threads: thread b handles batch b; wave-reduce the mean.
__global__ void finish_kernel(const float* __restrict__ ws, float* __restrict__ out)
{
    const int b = threadIdx.x;   // 0..63
    const float* num_ap = ws + WS_NUM_AP;
    const float* num_an = ws + WS_NUM_AN;
    const float* cnt_ap = ws + WS_CNT_AP;
    const float* cnt_an = ws + WS_CNT_AN;

    float ap = 3.4e38f, an = 3.4e38f;
#pragma unroll
    for (int s = 0; s < NOFF; ++s) {
        ap = fminf(ap, num_ap[b * NOFF + s] / (16.f * cnt_ap[b * NOFF + s] + 0.001f));
        an = fminf(an, num_an[b * NOFF + s] / (16.f * cnt_an[b * NOFF + s] + 0.001f));
    }
    float loss = fmaxf(ap - an + 0.15f, 0.f);
    loss = wave_sum_f(loss);
    if (b == 0) out[0] = loss * (1.0f / 64.f);
}

extern "C" void kernel_launch(void* const* d_in, const int* in_sizes, int n_in,
                              void* d_out, int out_size, void* d_ws, size_t ws_size,
                              hipStream_t stream) {
    const float* a = (const float*)d_in[0];
    const float* p = (const float*)d_in[1];
    const float* n = (const float*)d_in[2];
    const int* ma = (const int*)d_in[3];
    const int* mp = (const int*)d_in[4];
    const int* mn = (const int*)d_in[5];
    float* ws = (float*)d_ws;
    float* out = (float*)d_out;

    // ws is poisoned 0xAA before every timed launch — zero the accumulators.
    hipMemsetAsync(d_ws, 0, WS_FLOATS * sizeof(float), stream);

    num_kernel<<<dim3(16, NB), 256, 0, stream>>>(a, p, n, ma, mp, mn, ws);
    finish_kernel<<<1, 64, 0, stream>>>(ws, out);
}